// Round 4
// baseline (447.243 us; speedup 1.0000x reference)
//
#include <hip/hip_runtime.h>
#include <cstdint>
#include <cstddef>

typedef unsigned short u16;
typedef __attribute__((ext_vector_type(8))) __bf16 bf16x8;
typedef __attribute__((ext_vector_type(4))) float f32x4;
typedef __attribute__((ext_vector_type(4))) short s16x4;

#define SEQ 1024
#define MROWS 4096
#define DDIM 768
#define HID 769
#define KP1 800
#define MLPD 3072
#define KP2 3104
#define NHEADS 12
#define LN2F 0.69314718056f
#define LOG2EF 1.44269504089f

static __device__ __forceinline__ u16 f2bf(float f){
  union { float f; uint32_t u; } v; v.f = f;
  return (u16)((v.u + 0x7FFFu + ((v.u >> 16) & 1u)) >> 16);
}

static __device__ __forceinline__ f32x4 mfma16(bf16x8 a, bf16x8 b, f32x4 c){
  return __builtin_amdgcn_mfma_f32_16x16x32_bf16(a, b, c, 0, 0, 0);
}

static __device__ __forceinline__ f32x4 mfma16k(s16x4 a, s16x4 b, f32x4 c){
  return __builtin_amdgcn_mfma_f32_16x16x16bf16_1k(a, b, c, 0, 0, 0);
}

static __device__ __forceinline__ s16x4 pack4(uint32_t lo, uint32_t hi){
  union { uint2 u; s16x4 v; } cv; cv.u.x = lo; cv.u.y = hi; return cv.v;
}

static __device__ __forceinline__ void async_lds16(const u16* g, u16* l){
  u16* gm = const_cast<u16*>(g);
  __builtin_amdgcn_global_load_lds(
      (__attribute__((address_space(1))) void*)gm,
      (__attribute__((address_space(3))) void*)l, 16, 0, 0);
}

static __device__ __forceinline__ float blk_reduce(float v, float* red, int tid){
  #pragma unroll
  for (int off = 1; off < 64; off <<= 1) v += __shfl_xor(v, off, 64);
  __syncthreads();
  if ((tid & 63) == 0) red[tid >> 6] = v;
  __syncthreads();
  return red[0] + red[1] + red[2] + red[3];
}

// ---------------- all weight conversions in ONE kernel --------------
static __device__ __forceinline__ void conv_seg(const float* W, u16* O, int idx, int K, int Kp){
  int n = idx / Kp, k = idx - n * Kp;
  O[idx] = (k < K) ? f2bf(W[(size_t)n * K + k]) : (u16)0;
}
__global__ __launch_bounds__(256) void conv_all(const float* __restrict__ Wq, const float* __restrict__ Wk,
    const float* __restrict__ Wv, const float* __restrict__ Wo,
    const float* __restrict__ Wm1, const float* __restrict__ Wm2, u16* __restrict__ dst){
  int b = blockIdx.x, tid = threadIdx.x;
  if (b < 2400){        conv_seg(Wq,  dst,            b*256+tid,        769, 800); }
  else if (b < 4800){   conv_seg(Wk,  dst + 614400,  (b-2400)*256+tid,  769, 800); }
  else if (b < 7200){   conv_seg(Wv,  dst + 1228800, (b-4800)*256+tid,  769, 800); }
  else if (b < 9600){   conv_seg(Wo,  dst + 1843200, (b-7200)*256+tid,  769, 800); }
  else if (b < 19200){  conv_seg(Wm1, dst + 2457600, (b-9600)*256+tid,  769, 800); }
  else {                conv_seg(Wm2, dst + 4915200, (b-19200)*256+tid, 3073, 3104); }
}

// ---------------- lorentz layernorm -> bf16 [m][800] (col0 = t) -----
__global__ __launch_bounds__(256) void ln_kernel(const float* __restrict__ X, int xstr, int xoff,
    const float* __restrict__ g, const float* __restrict__ b, u16* __restrict__ O){
  __shared__ float red[4];
  int m = blockIdx.x, tid = threadIdx.x;
  const float* xr = X + (size_t)m * xstr + xoff;
  float s[3], y[3];
  float s1 = 0.f, s2 = 0.f;
  #pragma unroll
  for (int j = 0; j < 3; j++){ float v = xr[tid + j*256]; s[j] = v; s1 += v; s2 += v*v; }
  s1 = blk_reduce(s1, red, tid);
  s2 = blk_reduce(s2, red, tid);
  float mu = s1 * (1.f/768.f);
  float var = s2 * (1.f/768.f) - mu*mu;
  float rstd = rsqrtf(var + 1e-5f);
  float q = 0.f;
  #pragma unroll
  for (int j = 0; j < 3; j++){ int i = tid + j*256; y[j] = (s[j]-mu)*rstd*g[i] + b[i]; q += y[j]*y[j]; }
  q = blk_reduce(q, red, tid);
  u16* orow = O + (size_t)m * KP1;
  #pragma unroll
  for (int j = 0; j < 3; j++) orow[1 + tid + j*256] = f2bf(y[j]);
  if (tid == 0) orow[0] = f2bf(sqrtf(1.f + q));
  if (tid < 31) orow[769 + tid] = 0;
}

// ---------------- sum 4 partials + residual, then lorentz LN --------
__global__ __launch_bounds__(256) void ln_sum_kernel(const float* __restrict__ P4,
    const float* __restrict__ x, const float* __restrict__ g, const float* __restrict__ b,
    float* __restrict__ out1, u16* __restrict__ O){
  __shared__ float red[4];
  int m = blockIdx.x, tid = threadIdx.x;
  float s[3], y[3];
  float s1 = 0.f, s2 = 0.f;
  #pragma unroll
  for (int j = 0; j < 3; j++){
    int col = tid + j*256;
    float v = x[(size_t)m * HID + 1 + col];
    #pragma unroll
    for (int z = 0; z < 4; z++) v += P4[(size_t)z*MROWS*DDIM + (size_t)m*DDIM + col];
    out1[(size_t)m*DDIM + col] = v;
    s[j] = v; s1 += v; s2 += v*v;
  }
  s1 = blk_reduce(s1, red, tid);
  s2 = blk_reduce(s2, red, tid);
  float mu = s1 * (1.f/768.f);
  float var = s2 * (1.f/768.f) - mu*mu;
  float rstd = rsqrtf(var + 1e-5f);
  float q = 0.f;
  #pragma unroll
  for (int j = 0; j < 3; j++){ int i = tid + j*256; y[j] = (s[j]-mu)*rstd*g[i] + b[i]; q += y[j]*y[j]; }
  q = blk_reduce(q, red, tid);
  u16* orow = O + (size_t)m * KP1;
  #pragma unroll
  for (int j = 0; j < 3; j++) orow[1 + tid + j*256] = f2bf(y[j]);
  if (tid == 0) orow[0] = f2bf(sqrtf(1.f + q));
  if (tid < 31) orow[769 + tid] = 0;
}

// ---------------- 128x128 bf16 GEMM, split-K via z ------------------
__global__ __launch_bounds__(256) void gemm_split(
    const u16* __restrict__ A, const u16* __restrict__ B, float* __restrict__ C,
    int N, int Kp)
{
  __shared__ u16 As[128*32];
  __shared__ u16 Bs[128*32];
  int tid = threadIdx.x;
  int wave = tid >> 6, lane = tid & 63;
  int lrow = lane & 15, lq = lane >> 4;
  int m0 = blockIdx.y * 128, n0 = blockIdx.x * 128;
  int wm = wave >> 1, wn = wave & 1;
  int chunks = Kp >> 5;
  int nz = gridDim.z, z = blockIdx.z;
  int base = chunks / nz, rem = chunks - base * nz;
  int begin = z * base + (z < rem ? z : rem);
  int count = base + (z < rem ? 1 : 0);
  C += (size_t)z * MROWS * N;
  f32x4 acc[4][4] = {};
  int seg = wave * 2;
  int srow = lane >> 2;
  int scol = (lane & 3) * 8;
  const u16* Abase = A + (size_t)m0 * Kp;
  const u16* Bbase = B + (size_t)n0 * Kp;
  for (int kc = begin; kc < begin + count; kc++){
    int k0 = kc * 32;
    __syncthreads();
    #pragma unroll
    for (int i = 0; i < 2; i++){
      int s = seg + i;
      async_lds16(Abase + (size_t)(s*16 + srow) * Kp + k0 + scol, As + s*512);
      async_lds16(Bbase + (size_t)(s*16 + srow) * Kp + k0 + scol, Bs + s*512);
    }
    __syncthreads();
    bf16x8 af[4], bfr[4];
    #pragma unroll
    for (int t = 0; t < 4; t++){
      af[t]  = *(const bf16x8*)(As + (wm*64 + t*16 + lrow)*32 + lq*8);
      bfr[t] = *(const bf16x8*)(Bs + (wn*64 + t*16 + lrow)*32 + lq*8);
    }
    #pragma unroll
    for (int mt = 0; mt < 4; mt++)
      #pragma unroll
      for (int nt = 0; nt < 4; nt++)
        acc[mt][nt] = mfma16(af[mt], bfr[nt], acc[mt][nt]);
  }
  #pragma unroll
  for (int mt = 0; mt < 4; mt++)
    #pragma unroll
    for (int nt = 0; nt < 4; nt++){
      int col = n0 + wn*64 + nt*16 + lrow;
      #pragma unroll
      for (int r = 0; r < 4; r++){
        int row = m0 + wm*64 + mt*16 + lq*4 + r;
        C[(size_t)row * N + col] = acc[mt][nt][r];
      }
    }
}

// ---------------- pack Q/K heads from merged [m][2304] --------------
__global__ __launch_bounds__(256) void pack_qk(const float* __restrict__ raw,
    u16* __restrict__ Qp, u16* __restrict__ Kpk, float* __restrict__ qt, float* __restrict__ kt)
{
  int wave = threadIdx.x >> 6, lane = threadIdx.x & 63;
  int m = blockIdx.x * 4 + wave;
  int h = blockIdx.y;
  int which = blockIdx.z;
  const float* src = raw + (size_t)m * 2304 + which * 768 + h*64 + lane;
  float v = *src;
  float ss = v*v;
  #pragma unroll
  for (int off = 1; off < 64; off <<= 1) ss += __shfl_xor(ss, off, 64);
  int b = m >> 10, n = m & 1023, bh = b * NHEADS + h;
  u16* dst = (which ? Kpk : Qp) + ((size_t)bh * SEQ + n) * 64 + lane;
  *dst = f2bf(v);
  if (lane == 0) (which ? kt : qt)[bh * SEQ + n] = sqrtf(1.f + ss);
}

// ---------------- pack V: logmap0, transposed bf16 [bh][dim][key] ---
__global__ __launch_bounds__(256) void pack_v(const float* __restrict__ vraw, u16* __restrict__ Vt){
  __shared__ float part[256];
  __shared__ float scl[64];
  __shared__ float tile[64][65];
  int tid = threadIdx.x;
  int kb = blockIdx.x, bh = blockIdx.y;
  int b = bh / NHEADS, h = bh - b*NHEADS;
  int kl = tid >> 2;
  int d0 = (tid & 3) * 16;
  int m = b * SEQ + kb * 64 + kl;
  float v[16]; float ss = 0.f;
  const float* src = vraw + (size_t)m * 2304 + h*64 + d0;
  #pragma unroll
  for (int i = 0; i < 16; i++){ v[i] = src[i]; ss += v[i]*v[i]; }
  part[tid] = ss;
  __syncthreads();
  if ((tid & 3) == 0){
    float s2 = part[tid] + part[tid+1] + part[tid+2] + part[tid+3];
    float sn = sqrtf(s2);
    float tv = sqrtf(1.f + s2);
    float ctv = fmaxf(tv, 1.f + 1e-7f);
    float dist = __logf(ctv + sqrtf(fmaxf(ctv*ctv - 1.f, 0.f)));
    scl[kl] = dist / fmaxf(sn, 1e-8f);
  }
  __syncthreads();
  float sc = scl[kl];
  #pragma unroll
  for (int i = 0; i < 16; i++) tile[kl][d0 + i] = v[i] * sc;
  __syncthreads();
  int dim = tid >> 2;
  int kk0 = (tid & 3) * 16;
  u16 tmp[16];
  #pragma unroll
  for (int i = 0; i < 16; i++) tmp[i] = f2bf(tile[kk0 + i][dim]);
  u16* dst = Vt + ((size_t)bh * 64 + dim) * SEQ + kb*64 + kk0;
  *(uint4*)dst       = *(const uint4*)tmp;
  *(uint4*)(dst + 8) = *(const uint4*)(tmp + 8);
}

// ---------------- fused hyperbolic attention, no-LDS P path ---------
// grid (16 qblocks, 48 bh, 4 ksplit); partial sums out (no normalize).
// S^T via K-as-A/Q-as-B; P stays in registers as B-operand of
// mfma_16x16x16bf16 with Vt as A-operand (computes O^T).
__global__ __launch_bounds__(256) void attn_kernel(
    const u16* __restrict__ Q, const u16* __restrict__ K, const u16* __restrict__ Vt,
    const float* __restrict__ qt, const float* __restrict__ kt,
    float* __restrict__ pAggA, float* __restrict__ pAggB, float* __restrict__ pDen,
    const float* __restrict__ a_raw, const float* __restrict__ t_raw, const float* __restrict__ l_raw)
{
  __shared__ float rv[4][64];
  int tid = threadIdx.x;
  int bh = blockIdx.y, ks = blockIdx.z;
  int qbase = blockIdx.x * 64;
  float alpha = __logf(1.f + __expf(a_raw[0]));
  float tau   = __logf(1.f + __expf(t_raw[0]));
  float lam   = __logf(1.f + __expf(l_raw[0]));
  if (tid < 64){
    float qtv = qt[bh * SEQ + qbase + tid];
    float cq = fmaxf(qtv, 1.f + 1e-7f);
    float A = cq + __builtin_amdgcn_sqrtf(fmaxf(cq*cq - 1.f, 0.f)); // e^arccosh(cq)
    float ct = fminf(__builtin_amdgcn_logf(A) * LN2F, 40.f);
    float e = __expf(ct);
    float sh = 0.5f * (e - __builtin_amdgcn_rcpf(e));
    float ac = alpha * ct;
    rv[0][tid] = qtv;
    rv[1][tid] = cq;
    rv[2][tid] = __builtin_amdgcn_rcpf(sh);
    rv[3][tid] = (ac * __builtin_amdgcn_rcpf(1.f + ac) - 0.1f) * LOG2EF; // (B-0.1)*log2e
  }
  __syncthreads();
  int wave = tid >> 6, lane = tid & 63;
  int lrow = lane & 15, lq = lane >> 4;
  int myrow = wave*16 + lrow;
  float qt_l = rv[0][myrow], cq_l = rv[1][myrow], rri_l = rv[2][myrow], Bw_l = rv[3][myrow];
  const float tbase = tau * 0.92967051f;  // tau * softplus(-0.1)*log2e
  // Q as B-operand of K=32 mfma: lane holds Q[qrow=lrow][k=lq*8+j]
  const u16* Qb = Q + ((size_t)bh * SEQ + qbase + wave*16 + lrow) * 64 + lq*8;
  bf16x8 bq0 = *(const bf16x8*)Qb;
  bf16x8 bq1 = *(const bf16x8*)(Qb + 32);
  const u16* Kh = K + (size_t)bh * SEQ * 64;
  const u16* Vh = Vt + (size_t)bh * 64 * SEQ;
  const float* ktp = kt + (size_t)bh * SEQ;
  f32x4 o[4] = {};   // O^T: lane holds O[qrow=lrow][dim = nt*16 + lq*4 + r]
  float dsum = 0.f;
  for (int jt = 0; jt < 4; jt++){
    int jbase = ks * 256 + jt * 64;
    f32x4 s[4];
    #pragma unroll
    for (int ct = 0; ct < 4; ct++){
      const u16* Ka = Kh + (size_t)(jbase + ct*16 + lrow) * 64 + lq*8;
      bf16x8 a0 = *(const bf16x8*)Ka;
      bf16x8 a1 = *(const bf16x8*)(Ka + 32);
      f32x4 z = {0.f, 0.f, 0.f, 0.f};
      z = mfma16(a0, bq0, z);
      z = mfma16(a1, bq1, z);
      s[ct] = z;    // S[key = ct*16 + lq*4 + r][qrow = lrow]
    }
    s16x4 pb[4];
    #pragma unroll
    for (int ct = 0; ct < 4; ct++){
      float4 kv = *(const float4*)(ktp + jbase + ct*16 + lq*4);
      uint32_t pu[4];
      #pragma unroll
      for (int r = 0; r < 4; r++){
        float ktv = (r == 0) ? kv.x : (r == 1) ? kv.y : (r == 2) ? kv.z : kv.w;
        float c = fmaxf(__builtin_fmaf(qt_l, ktv, -s[ct][r]), 1.f);
        bool self = c < 1.00001f;
        float ce = self ? 2.f : c;
        float cm1 = __builtin_fmaf(ce, ce, -1.f);
        float rs = __builtin_amdgcn_rsqf(cm1);
        float shq = cm1 * rs;                       // sinh(arccosh(ce))
        float d = __builtin_amdgcn_logf(ce + shq) * LN2F;  // arccosh(ce) (< ~9, no clamp needed)
        float L1 = __builtin_amdgcn_logf(__builtin_fmaf(d, d, 1.f));
        float Z = __builtin_fmaf(ce, cq_l, -ktv) * rri_l * rs;
        Z = fminf(fmaxf(Z, -1.f), 1.f);
        Z = self ? 1.f : Z;
        float w2 = __builtin_fmaf(Z, LOG2EF, Bw_l);
        float ew = __builtin_amdgcn_exp2f(w2);
        float L2 = __builtin_amdgcn_logf(ew + 1.f);
        float logit = __builtin_fmaf(-lam, L1, __builtin_fmaf(-tau, L2, tbase));
        float p = __builtin_amdgcn_exp2f(logit);
        uint32_t u = __float_as_uint(p);
        pu[r] = u;
        dsum += __uint_as_float(u & 0xFFFF0000u);   // den over truncated weights
      }
      uint32_t lo = __builtin_amdgcn_perm(pu[1], pu[0], 0x07060302u);
      uint32_t hi = __builtin_amdgcn_perm(pu[3], pu[2], 0x07060302u);
      pb[ct] = pack4(lo, hi);   // B-frag: P[key=ct*16+lq*4+j][qrow=lrow]
    }
    #pragma unroll
    for (int ct = 0; ct < 4; ct++){
      #pragma unroll
      for (int nt = 0; nt < 4; nt++){
        // A-frag: Vt[dim = nt*16 + lrow][key = jbase + ct*16 + lq*4 + j]
        s16x4 va = *(const s16x4*)(Vh + (size_t)(nt*16 + lrow) * SEQ + jbase + ct*16 + lq*4);
        o[nt] = mfma16k(va, pb[ct], o[nt]);
      }
    }
  }
  // den: lanes lrow, lrow+16, +32, +48 hold same qrow -> reduce over lq
  dsum += __shfl_xor(dsum, 16, 64);
  dsum += __shfl_xor(dsum, 32, 64);
  float* pAgg = (ks < 2) ? (pAggA + (size_t)ks * 48 * SEQ * 64)
                         : (pAggB + (size_t)(ks - 2) * 48 * SEQ * 64);
  size_t rowb = (size_t)bh * SEQ + qbase + wave*16 + lrow;
  if (lq == 0) pDen[(size_t)ks * 48 * SEQ + rowb] = dsum;
  #pragma unroll
  for (int nt = 0; nt < 4; nt++){
    float4 ov; ov.x = o[nt][0]; ov.y = o[nt][1]; ov.z = o[nt][2]; ov.w = o[nt][3];
    *(float4*)(pAgg + rowb * 64 + nt*16 + lq*4) = ov;
  }
}

// ---------------- reduce 4 splits + expmap0 + t_new -> bf16 [m][800]
__global__ __launch_bounds__(768) void expmap_pack(const float* __restrict__ pAggA,
    const float* __restrict__ pAggB, const float* __restrict__ pDen, u16* __restrict__ O){
  __shared__ float th2[NHEADS];
  int m = blockIdx.x, tid = threadIdx.x;
  int h = tid >> 6, lane = tid & 63;
  int b = m >> 10, n = m & 1023, bh = b*NHEADS + h;
  size_t base = (size_t)bh * SEQ + n;
  float d = pDen[base] + pDen[(size_t)48*SEQ + base]
          + pDen[(size_t)96*SEQ + base] + pDen[(size_t)144*SEQ + base];
  float rden = __builtin_amdgcn_rcpf(d * (1.f + 1e-8f));
  float u = pAggA[base*64 + lane] + pAggA[((size_t)48*SEQ + base)*64 + lane]
          + pAggB[base*64 + lane] + pAggB[((size_t)48*SEQ + base)*64 + lane];
  u *= rden;
  float n2 = u*u;
  #pragma unroll
  for (int off = 1; off < 64; off <<= 1) n2 += __shfl_xor(n2, off, 64);
  float nn = sqrtf(n2);
  float e = __expf(nn);
  float ch = 0.5f * (e + 1.f/e);
  float sh = 0.5f * (e - 1.f/e);
  float sc = sh / fmaxf(nn, 1e-8f);
  u16* orow = O + (size_t)m * KP1;
  orow[1 + h*64 + lane] = f2bf(u * sc);
  if (lane == 0) th2[h] = ch*ch;
  __syncthreads();
  if (tid == 0){
    float ssum = 0.f;
    #pragma unroll
    for (int i = 0; i < NHEADS; i++) ssum += th2[i];
    orow[0] = f2bf(sqrtf(ssum - 11.f));
  }
  if (tid >= 1 && tid < 32) orow[768 + tid] = 0;
}

// ---------------- exact GELU + add_time -> bf16 [m][3104] -----------
__global__ __launch_bounds__(256) void gelu_pack(const float* __restrict__ Zin, u16* __restrict__ O){
  __shared__ float red[4];
  int m = blockIdx.x, tid = threadIdx.x;
  const float* zr = Zin + (size_t)m * MLPD;
  float gv[12]; float gs = 0.f;
  #pragma unroll
  for (int j = 0; j < 12; j++){
    float z = zr[tid + j*256];
    float e = 0.5f * z * (1.f + erff(z * 0.70710678f));
    gv[j] = e; gs += e*e;
  }
  gs = blk_reduce(gs, red, tid);
  u16* orow = O + (size_t)m * KP2;
  #pragma unroll
  for (int j = 0; j < 12; j++) orow[1 + tid + j*256] = f2bf(gv[j]);
  if (tid == 0) orow[0] = f2bf(sqrtf(1.f + gs));
  if (tid < 31) orow[3073 + tid] = 0;
}

// ---------------- sum 4 partials + residual + add_time -> d_out -----
__global__ __launch_bounds__(256) void final_sum(const float* __restrict__ P4,
    const float* __restrict__ out1, float* __restrict__ out){
  __shared__ float red[4];
  int m = blockIdx.x, tid = threadIdx.x;
  float v[3]; float s2 = 0.f;
  #pragma unroll
  for (int j = 0; j < 3; j++){
    int col = tid + j*256;
    float t = out1[(size_t)m*DDIM + col];
    #pragma unroll
    for (int z = 0; z < 4; z++) t += P4[(size_t)z*MROWS*DDIM + (size_t)m*DDIM + col];
    v[j] = t; s2 += t*t;
  }
  s2 = blk_reduce(s2, red, tid);
  float* orow = out + (size_t)m * HID;
  if (tid == 0) orow[0] = sqrtf(1.f + s2);
  #pragma unroll
  for (int j = 0; j < 3; j++) orow[1 + tid + j*256] = v[j];
}

extern "C" void kernel_launch(void* const* d_in, const int* in_sizes, int n_in,
                              void* d_out, int out_size, void* d_ws, size_t ws_size,
                              hipStream_t stream)
{
  (void)in_sizes; (void)n_in; (void)out_size; (void)ws_size;
  const float* x   = (const float*)d_in[0];
  const float* Wq  = (const float*)d_in[1];
  const float* Wk  = (const float*)d_in[2];
  const float* Wv  = (const float*)d_in[3];
  const float* Wo  = (const float*)d_in[4];
  const float* g1p = (const float*)d_in[5];
  const float* b1p = (const float*)d_in[6];
  const float* g2p = (const float*)d_in[7];
  const float* b2p = (const float*)d_in[8];
  const float* Wm1 = (const float*)d_in[9];
  const float* Wm2 = (const float*)d_in[10];
  const float* ar  = (const float*)d_in[11];
  const float* tr  = (const float*)d_in[12];
  const float* lr  = (const float*)d_in[13];

  char* ws = (char*)d_ws;
  // weights [0, 14,598,144)
  u16*   wqb  = (u16*)(ws + 0);          // wk,wv contiguous after (merged B)
  u16*   wob  = (u16*)(ws + 3686400);
  u16*   wm1b = (u16*)(ws + 4915200);
  u16*   wm2b = (u16*)(ws + 9830400);
  u16*   xln  = (u16*)(ws + 14598144);   // 6.55 MB  [ln -> gemm qkv]
  float* qkv  = (float*)(ws + 21151744); // 37.75 MB [gemm qkv -> packs]
  u16*   qp   = (u16*)(ws + 58900480);   // 6.29 MB  [-> attn]
  u16*   kpk  = (u16*)(ws + 65191936);   // 6.29 MB  [-> attn]
  u16*   vt   = (u16*)(ws + 71483392);   // 6.29 MB  [-> attn]
  float* qtb  = (float*)(ws + 77774848);
  float* ktb  = (float*)(ws + 77971456);
  float* pAggA= (float*)(ws + 14598144); // z0,1: 25.17 MB, alias xln+qkv-head (dead)
  float* pAggB= (float*)(ws + 78168064); // z2,3: 25.17 MB -> end 103,333,888
  float* pDen = (float*)(ws + 103333888);// 786 KB -> 104,120,320
  u16*   woin = (u16*)(ws + 104120320);  // 6.55 MB -> 110,673,920  [expmap -> gemm Wo]
  float* woP  = (float*)(ws + 14598144); // 50.33 MB, alias pAggA+qkv (dead) [-> ln_sum]
  float* out1 = (float*)(ws + 64929792); // 12.58 MB, alias qp.. (dead) [-> final]
  u16*   ln2b = (u16*)(ws + 77512704);   // 6.55 MB, alias qtb/ktb/pAggB-head (dead)
  float* mlp1 = (float*)(ws + 14598144); // 50.33 MB, alias woP (dead)
  u16*   g1b  = (u16*)(ws + 84066304);   // 25.43 MB -> 109,494,272 (pAggB/pDen/woin dead)
  float* out2P= (float*)(ws + 14598144); // 50.33 MB, alias mlp1 (dead)

  conv_all<<<dim3(28512), 256, 0, stream>>>(Wq, Wk, Wv, Wo, Wm1, Wm2, wqb);
  ln_kernel<<<dim3(4096), 256, 0, stream>>>(x, 769, 1, g1p, b1p, xln);
  gemm_split<<<dim3(18, 32, 1), 256, 0, stream>>>(xln, wqb, qkv, 2304, 800);
  pack_qk<<<dim3(1024, 12, 2), 256, 0, stream>>>(qkv, qp, kpk, qtb, ktb);
  pack_v<<<dim3(16, 48), 256, 0, stream>>>(qkv + 1536, vt);
  attn_kernel<<<dim3(16, 48, 4), 256, 0, stream>>>(qp, kpk, vt, qtb, ktb, pAggA, pAggB, pDen, ar, tr, lr);
  expmap_pack<<<dim3(4096), 768, 0, stream>>>(pAggA, pAggB, pDen, woin);
  gemm_split<<<dim3(6, 32, 4), 256, 0, stream>>>(woin, wob, woP, 768, 800);
  ln_sum_kernel<<<dim3(4096), 256, 0, stream>>>(woP, x, g2p, b2p, out1, ln2b);
  gemm_split<<<dim3(24, 32, 1), 256, 0, stream>>>(ln2b, wm1b, mlp1, 3072, 800);
  gelu_pack<<<dim3(4096), 256, 0, stream>>>(mlp1, g1b);
  gemm_split<<<dim3(6, 32, 4), 256, 0, stream>>>(g1b, wm2b, out2P, 768, 3104);
  final_sum<<<dim3(4096), 256, 0, stream>>>(out2P, out1, (float*)d_out);
}

// Round 5
// 374.743 us; speedup vs baseline: 1.1935x; 1.1935x over previous
//
#include <hip/hip_runtime.h>
#include <cstdint>
#include <cstddef>

typedef unsigned short u16;
typedef __attribute__((ext_vector_type(8))) __bf16 bf16x8;
typedef __attribute__((ext_vector_type(4))) float f32x4;
typedef __attribute__((ext_vector_type(4))) short s16x4;

#define SEQ 1024
#define MROWS 4096
#define DDIM 768
#define HID 769
#define KP1 800
#define MLPD 3072
#define KP2 3104
#define NHEADS 12
#define LN2F 0.69314718056f
#define LOG2EF 1.44269504089f

static __device__ __forceinline__ u16 f2bf(float f){
  union { float f; uint32_t u; } v; v.f = f;
  return (u16)((v.u + 0x7FFFu + ((v.u >> 16) & 1u)) >> 16);
}

static __device__ __forceinline__ f32x4 mfma16(bf16x8 a, bf16x8 b, f32x4 c){
  return __builtin_amdgcn_mfma_f32_16x16x32_bf16(a, b, c, 0, 0, 0);
}

static __device__ __forceinline__ f32x4 mfma16k(s16x4 a, s16x4 b, f32x4 c){
  return __builtin_amdgcn_mfma_f32_16x16x16bf16_1k(a, b, c, 0, 0, 0);
}

static __device__ __forceinline__ s16x4 pack4(uint32_t lo, uint32_t hi){
  union { uint2 u; s16x4 v; } cv; cv.u.x = lo; cv.u.y = hi; return cv.v;
}

static __device__ __forceinline__ void async_lds16(const u16* g, u16* l){
  u16* gm = const_cast<u16*>(g);
  __builtin_amdgcn_global_load_lds(
      (__attribute__((address_space(1))) void*)gm,
      (__attribute__((address_space(3))) void*)l, 16, 0, 0);
}

static __device__ __forceinline__ float blk_reduce(float v, float* red, int tid){
  #pragma unroll
  for (int off = 1; off < 64; off <<= 1) v += __shfl_xor(v, off, 64);
  __syncthreads();
  if ((tid & 63) == 0) red[tid >> 6] = v;
  __syncthreads();
  return red[0] + red[1] + red[2] + red[3];
}

// ---------------- all weight conversions in ONE kernel --------------
static __device__ __forceinline__ void conv_seg(const float* W, u16* O, int idx, int K, int Kp){
  int n = idx / Kp, k = idx - n * Kp;
  O[idx] = (k < K) ? f2bf(W[(size_t)n * K + k]) : (u16)0;
}
__global__ __launch_bounds__(256) void conv_all(const float* __restrict__ Wq, const float* __restrict__ Wk,
    const float* __restrict__ Wv, const float* __restrict__ Wo,
    const float* __restrict__ Wm1, const float* __restrict__ Wm2, u16* __restrict__ dst){
  int b = blockIdx.x, tid = threadIdx.x;
  if (b < 2400){        conv_seg(Wq,  dst,            b*256+tid,        769, 800); }
  else if (b < 4800){   conv_seg(Wk,  dst + 614400,  (b-2400)*256+tid,  769, 800); }
  else if (b < 7200){   conv_seg(Wv,  dst + 1228800, (b-4800)*256+tid,  769, 800); }
  else if (b < 9600){   conv_seg(Wo,  dst + 1843200, (b-7200)*256+tid,  769, 800); }
  else if (b < 19200){  conv_seg(Wm1, dst + 2457600, (b-9600)*256+tid,  769, 800); }
  else {                conv_seg(Wm2, dst + 4915200, (b-19200)*256+tid, 3073, 3104); }
}

// ---------------- lorentz layernorm -> bf16 [m][800] (col0 = t) -----
__global__ __launch_bounds__(256) void ln_kernel(const float* __restrict__ X, int xstr, int xoff,
    const float* __restrict__ g, const float* __restrict__ b, u16* __restrict__ O){
  __shared__ float red[4];
  int m = blockIdx.x, tid = threadIdx.x;
  const float* xr = X + (size_t)m * xstr + xoff;
  float s[3], y[3];
  float s1 = 0.f, s2 = 0.f;
  #pragma unroll
  for (int j = 0; j < 3; j++){ float v = xr[tid + j*256]; s[j] = v; s1 += v; s2 += v*v; }
  s1 = blk_reduce(s1, red, tid);
  s2 = blk_reduce(s2, red, tid);
  float mu = s1 * (1.f/768.f);
  float var = s2 * (1.f/768.f) - mu*mu;
  float rstd = rsqrtf(var + 1e-5f);
  float q = 0.f;
  #pragma unroll
  for (int j = 0; j < 3; j++){ int i = tid + j*256; y[j] = (s[j]-mu)*rstd*g[i] + b[i]; q += y[j]*y[j]; }
  q = blk_reduce(q, red, tid);
  u16* orow = O + (size_t)m * KP1;
  #pragma unroll
  for (int j = 0; j < 3; j++) orow[1 + tid + j*256] = f2bf(y[j]);
  if (tid == 0) orow[0] = f2bf(sqrtf(1.f + q));
  if (tid < 31) orow[769 + tid] = 0;
}

// ---------------- sum 4 partials + residual, then lorentz LN --------
__global__ __launch_bounds__(256) void ln_sum_kernel(const float* __restrict__ P4,
    const float* __restrict__ x, const float* __restrict__ g, const float* __restrict__ b,
    float* __restrict__ out1, u16* __restrict__ O){
  __shared__ float red[4];
  int m = blockIdx.x, tid = threadIdx.x;
  float s[3], y[3];
  float s1 = 0.f, s2 = 0.f;
  #pragma unroll
  for (int j = 0; j < 3; j++){
    int col = tid + j*256;
    float v = x[(size_t)m * HID + 1 + col];
    #pragma unroll
    for (int z = 0; z < 4; z++) v += P4[(size_t)z*MROWS*DDIM + (size_t)m*DDIM + col];
    out1[(size_t)m*DDIM + col] = v;
    s[j] = v; s1 += v; s2 += v*v;
  }
  s1 = blk_reduce(s1, red, tid);
  s2 = blk_reduce(s2, red, tid);
  float mu = s1 * (1.f/768.f);
  float var = s2 * (1.f/768.f) - mu*mu;
  float rstd = rsqrtf(var + 1e-5f);
  float q = 0.f;
  #pragma unroll
  for (int j = 0; j < 3; j++){ int i = tid + j*256; y[j] = (s[j]-mu)*rstd*g[i] + b[i]; q += y[j]*y[j]; }
  q = blk_reduce(q, red, tid);
  u16* orow = O + (size_t)m * KP1;
  #pragma unroll
  for (int j = 0; j < 3; j++) orow[1 + tid + j*256] = f2bf(y[j]);
  if (tid == 0) orow[0] = f2bf(sqrtf(1.f + q));
  if (tid < 31) orow[769 + tid] = 0;
}

// ---------------- 128x128 bf16 GEMM, split-K via z ------------------
__global__ __launch_bounds__(256) void gemm_split(
    const u16* __restrict__ A, const u16* __restrict__ B, float* __restrict__ C,
    int N, int Kp)
{
  __shared__ u16 As[128*32];
  __shared__ u16 Bs[128*32];
  int tid = threadIdx.x;
  int wave = tid >> 6, lane = tid & 63;
  int lrow = lane & 15, lq = lane >> 4;
  int m0 = blockIdx.y * 128, n0 = blockIdx.x * 128;
  int wm = wave >> 1, wn = wave & 1;
  int chunks = Kp >> 5;
  int nz = gridDim.z, z = blockIdx.z;
  int base = chunks / nz, rem = chunks - base * nz;
  int begin = z * base + (z < rem ? z : rem);
  int count = base + (z < rem ? 1 : 0);
  C += (size_t)z * MROWS * N;
  f32x4 acc[4][4] = {};
  int seg = wave * 2;
  int srow = lane >> 2;
  int scol = (lane & 3) * 8;
  const u16* Abase = A + (size_t)m0 * Kp;
  const u16* Bbase = B + (size_t)n0 * Kp;
  for (int kc = begin; kc < begin + count; kc++){
    int k0 = kc * 32;
    __syncthreads();
    #pragma unroll
    for (int i = 0; i < 2; i++){
      int s = seg + i;
      async_lds16(Abase + (size_t)(s*16 + srow) * Kp + k0 + scol, As + s*512);
      async_lds16(Bbase + (size_t)(s*16 + srow) * Kp + k0 + scol, Bs + s*512);
    }
    __syncthreads();
    bf16x8 af[4], bfr[4];
    #pragma unroll
    for (int t = 0; t < 4; t++){
      af[t]  = *(const bf16x8*)(As + (wm*64 + t*16 + lrow)*32 + lq*8);
      bfr[t] = *(const bf16x8*)(Bs + (wn*64 + t*16 + lrow)*32 + lq*8);
    }
    #pragma unroll
    for (int mt = 0; mt < 4; mt++)
      #pragma unroll
      for (int nt = 0; nt < 4; nt++)
        acc[mt][nt] = mfma16(af[mt], bfr[nt], acc[mt][nt]);
  }
  #pragma unroll
  for (int mt = 0; mt < 4; mt++)
    #pragma unroll
    for (int nt = 0; nt < 4; nt++){
      int col = n0 + wn*64 + nt*16 + lrow;
      #pragma unroll
      for (int r = 0; r < 4; r++){
        int row = m0 + wm*64 + mt*16 + lq*4 + r;
        C[(size_t)row * N + col] = acc[mt][nt][r];
      }
    }
}

// ---------------- 128x128 bf16 GEMM + exact GELU -> bf16 [m][KP2] ---
__global__ __launch_bounds__(256) void gemm_gelu(
    const u16* __restrict__ A, const u16* __restrict__ B, u16* __restrict__ O,
    int N, int Kp)
{
  __shared__ u16 As[128*32];
  __shared__ u16 Bs[128*32];
  int tid = threadIdx.x;
  int wave = tid >> 6, lane = tid & 63;
  int lrow = lane & 15, lq = lane >> 4;
  int m0 = blockIdx.y * 128, n0 = blockIdx.x * 128;
  int wm = wave >> 1, wn = wave & 1;
  f32x4 acc[4][4] = {};
  int seg = wave * 2;
  int srow = lane >> 2;
  int scol = (lane & 3) * 8;
  const u16* Abase = A + (size_t)m0 * Kp;
  const u16* Bbase = B + (size_t)n0 * Kp;
  for (int k0 = 0; k0 < Kp; k0 += 32){
    __syncthreads();
    #pragma unroll
    for (int i = 0; i < 2; i++){
      int s = seg + i;
      async_lds16(Abase + (size_t)(s*16 + srow) * Kp + k0 + scol, As + s*512);
      async_lds16(Bbase + (size_t)(s*16 + srow) * Kp + k0 + scol, Bs + s*512);
    }
    __syncthreads();
    bf16x8 af[4], bfr[4];
    #pragma unroll
    for (int t = 0; t < 4; t++){
      af[t]  = *(const bf16x8*)(As + (wm*64 + t*16 + lrow)*32 + lq*8);
      bfr[t] = *(const bf16x8*)(Bs + (wn*64 + t*16 + lrow)*32 + lq*8);
    }
    #pragma unroll
    for (int mt = 0; mt < 4; mt++)
      #pragma unroll
      for (int nt = 0; nt < 4; nt++)
        acc[mt][nt] = mfma16(af[mt], bfr[nt], acc[mt][nt]);
  }
  #pragma unroll
  for (int mt = 0; mt < 4; mt++)
    #pragma unroll
    for (int nt = 0; nt < 4; nt++){
      int col = n0 + wn*64 + nt*16 + lrow;
      #pragma unroll
      for (int r = 0; r < 4; r++){
        int row = m0 + wm*64 + mt*16 + lq*4 + r;
        float v = acc[mt][nt][r];
        float e = 0.5f * v * (1.f + erff(v * 0.70710678f));
        O[(size_t)row * KP2 + 1 + col] = f2bf(e);
      }
    }
}

// ---------------- row sum of squares -> time col + pad --------------
__global__ __launch_bounds__(256) void rowsum(u16* __restrict__ O){
  __shared__ float red[4];
  int m = blockIdx.x, tid = threadIdx.x;
  u16* orow = O + (size_t)m * KP2;
  float gs = 0.f;
  #pragma unroll
  for (int j = 0; j < 12; j++){
    uint32_t u = orow[1 + tid + j*256];
    float e = __uint_as_float(u << 16);
    gs += e*e;
  }
  gs = blk_reduce(gs, red, tid);
  if (tid == 0) orow[0] = f2bf(sqrtf(1.f + gs));
  if (tid < 31) orow[3073 + tid] = 0;
}

// ---------------- pack Q/K heads from merged [m][2304] --------------
__global__ __launch_bounds__(256) void pack_qk(const float* __restrict__ raw,
    u16* __restrict__ Qp, u16* __restrict__ Kpk, float* __restrict__ qt, float* __restrict__ kt)
{
  int wave = threadIdx.x >> 6, lane = threadIdx.x & 63;
  int m = blockIdx.x * 4 + wave;
  int h = blockIdx.y;
  int which = blockIdx.z;
  const float* src = raw + (size_t)m * 2304 + which * 768 + h*64 + lane;
  float v = *src;
  float ss = v*v;
  #pragma unroll
  for (int off = 1; off < 64; off <<= 1) ss += __shfl_xor(ss, off, 64);
  int b = m >> 10, n = m & 1023, bh = b * NHEADS + h;
  u16* dst = (which ? Kpk : Qp) + ((size_t)bh * SEQ + n) * 64 + lane;
  *dst = f2bf(v);
  if (lane == 0) (which ? kt : qt)[bh * SEQ + n] = sqrtf(1.f + ss);
}

// ---------------- pack V: logmap0, MFMA-A-fragment order ------------
// Vf[bh][ctg(64)][ntp(2)][lane(64)][8 u16]:
//   low 8B  = V^T[dim = ntp*32 + (lane&15)][key = ctg*16 + (lane>>4)*4 + j]
//   high 8B = same with dim += 16
__global__ __launch_bounds__(256) void pack_v(const float* __restrict__ vraw, u16* __restrict__ Vf){
  __shared__ float part[256];
  __shared__ float scl[64];
  __shared__ float tile[64][65];
  int tid = threadIdx.x;
  int kb = blockIdx.x, bh = blockIdx.y;
  int b = bh / NHEADS, h = bh - b*NHEADS;
  int kl = tid >> 2;
  int d0 = (tid & 3) * 16;
  int m = b * SEQ + kb * 64 + kl;
  float v[16]; float ss = 0.f;
  const float* src = vraw + (size_t)m * 2304 + h*64 + d0;
  #pragma unroll
  for (int i = 0; i < 16; i++){ v[i] = src[i]; ss += v[i]*v[i]; }
  part[tid] = ss;
  __syncthreads();
  if ((tid & 3) == 0){
    float s2 = part[tid] + part[tid+1] + part[tid+2] + part[tid+3];
    float sn = sqrtf(s2);
    float tv = sqrtf(1.f + s2);
    float ctv = fmaxf(tv, 1.f + 1e-7f);
    float dist = __logf(ctv + sqrtf(fmaxf(ctv*ctv - 1.f, 0.f)));
    scl[kl] = dist / fmaxf(sn, 1e-8f);
  }
  __syncthreads();
  float sc = scl[kl];
  #pragma unroll
  for (int i = 0; i < 16; i++) tile[kl][d0 + i] = v[i] * sc;
  __syncthreads();
  #pragma unroll
  for (int i = 0; i < 2; i++){
    int idx = tid + i*256;           // [0,512)
    int ctg_l = idx >> 7;            // [0,4)
    int ntp = (idx >> 6) & 1;
    int ln  = idx & 63;
    int lr = ln & 15, lqq = ln >> 4;
    int k0 = ctg_l*16 + lqq*4;
    int dlo = ntp*32 + lr;
    u16 tmp[8];
    #pragma unroll
    for (int j = 0; j < 4; j++){
      tmp[j]     = f2bf(tile[k0+j][dlo]);
      tmp[4+j]   = f2bf(tile[k0+j][dlo+16]);
    }
    u16* dst = Vf + ((((size_t)bh*64 + kb*4 + ctg_l)*2 + ntp)*64 + ln)*8;
    *(uint4*)dst = *(const uint4*)tmp;
  }
}

// ---------------- fused hyperbolic attention --------------------------
// grid (16 qblocks, 48 bh, 2 ksplit). S^T via K-as-A/Q-as-B MFMA; P stays
// in registers as B-operand of 16x16x16 MFMA; V A-frags pre-laid-out in Vf
// (fully coalesced b128); denominator via ones-row MFMA.
__global__ __launch_bounds__(256) void attn_kernel(
    const u16* __restrict__ Q, const u16* __restrict__ K, const u16* __restrict__ Vf,
    const float* __restrict__ qt, const float* __restrict__ kt,
    float* __restrict__ pAgg, float* __restrict__ pDen,
    const float* __restrict__ a_raw, const float* __restrict__ t_raw, const float* __restrict__ l_raw)
{
  __shared__ float rv[4][64];
  int tid = threadIdx.x;
  int bh = blockIdx.y, ks = blockIdx.z;
  int qbase = blockIdx.x * 64;
  float alpha = __logf(1.f + __expf(a_raw[0]));
  float tau   = __logf(1.f + __expf(t_raw[0]));
  float lam   = __logf(1.f + __expf(l_raw[0]));
  if (tid < 64){
    float qtv = qt[bh * SEQ + qbase + tid];
    float cq = fmaxf(qtv, 1.f + 1e-7f);
    float A = cq + __builtin_amdgcn_sqrtf(fmaxf(cq*cq - 1.f, 0.f)); // e^arccosh(cq)
    float ct = fminf(__builtin_amdgcn_logf(A) * LN2F, 40.f);
    float e = __expf(ct);
    float sh = 0.5f * (e - __builtin_amdgcn_rcpf(e));
    float ac = alpha * ct;
    rv[0][tid] = qtv;
    rv[1][tid] = cq;
    rv[2][tid] = __builtin_amdgcn_rcpf(sh);
    rv[3][tid] = (ac * __builtin_amdgcn_rcpf(1.f + ac) - 0.1f) * LOG2EF; // (B-0.1)*log2e
  }
  __syncthreads();
  int wave = tid >> 6, lane = tid & 63;
  int lrow = lane & 15, lq = lane >> 4;
  int myrow = wave*16 + lrow;
  float qt_l = rv[0][myrow], cq_l = rv[1][myrow], rri_l = rv[2][myrow], Bw_l = rv[3][myrow];
  const float tbase = tau * 0.92967051f;  // tau * softplus(-0.1)*log2e
  const u16* Qb = Q + ((size_t)bh * SEQ + qbase + wave*16 + lrow) * 64 + lq*8;
  bf16x8 bq0 = *(const bf16x8*)Qb;
  bf16x8 bq1 = *(const bf16x8*)(Qb + 32);
  const u16* Kt = K + (size_t)bh * SEQ * 64 + (size_t)(ks*512 + lrow) * 64 + lq*8;
  const u16* Vp = Vf + (size_t)bh * 65536 + (size_t)(ks*32) * 1024 + lane*8;
  const float* ktp = kt + (size_t)bh * SEQ + ks*512 + lq*4;
  s16x4 ones;
  ones[0] = (short)0x3F80; ones[1] = (short)0x3F80; ones[2] = (short)0x3F80; ones[3] = (short)0x3F80;
  f32x4 o[4] = {};   // O^T: lane holds O[qrow=lrow][dim = nt*16 + lq*4 + r]
  f32x4 dacc = {};
  for (int jt = 0; jt < 8; jt++){
    // V fragments: 8 fully-coalesced b128 loads (consumed at bottom)
    bf16x8 vv[8];
    #pragma unroll
    for (int ct = 0; ct < 4; ct++){
      vv[ct*2]   = *(const bf16x8*)(Vp + ct*1024);
      vv[ct*2+1] = *(const bf16x8*)(Vp + ct*1024 + 512);
    }
    float4 kv[4];
    #pragma unroll
    for (int ct = 0; ct < 4; ct++) kv[ct] = *(const float4*)(ktp + ct*16);
    f32x4 s[4];
    #pragma unroll
    for (int ct = 0; ct < 4; ct++){
      bf16x8 a0 = *(const bf16x8*)(Kt + ct*1024);
      bf16x8 a1 = *(const bf16x8*)(Kt + ct*1024 + 32);
      f32x4 z = {0.f, 0.f, 0.f, 0.f};
      z = mfma16(a0, bq0, z);
      z = mfma16(a1, bq1, z);
      s[ct] = z;    // S[key = ct*16 + lq*4 + r][qrow = lrow]
    }
    #pragma unroll
    for (int ct = 0; ct < 4; ct++){
      float4 kvv = kv[ct];
      uint32_t pu[4];
      #pragma unroll
      for (int r = 0; r < 4; r++){
        float ktv = (r == 0) ? kvv.x : (r == 1) ? kvv.y : (r == 2) ? kvv.z : kvv.w;
        float c = fmaxf(__builtin_fmaf(qt_l, ktv, -s[ct][r]), 1.f);
        bool self = c < 1.00001f;
        float ce = self ? 2.f : c;
        float cm1 = __builtin_fmaf(ce, ce, -1.f);
        float rs = __builtin_amdgcn_rsqf(cm1);
        float shq = cm1 * rs;                       // sinh(arccosh(ce))
        float d = __builtin_amdgcn_logf(ce + shq) * LN2F;  // arccosh(ce)
        float L1 = __builtin_amdgcn_logf(__builtin_fmaf(d, d, 1.f));
        float Z = __builtin_fmaf(ce, cq_l, -ktv) * rri_l * rs;
        Z = fminf(fmaxf(Z, -1.f), 1.f);
        Z = self ? 1.f : Z;
        float w2 = __builtin_fmaf(Z, LOG2EF, Bw_l);
        float ew = __builtin_amdgcn_exp2f(w2);
        float L2 = __builtin_amdgcn_logf(ew + 1.f);
        float logit = __builtin_fmaf(-lam, L1, __builtin_fmaf(-tau, L2, tbase));
        float p = __builtin_amdgcn_exp2f(logit);
        pu[r] = __float_as_uint(p);
      }
      uint32_t lo = __builtin_amdgcn_perm(pu[1], pu[0], 0x07060302u);
      uint32_t hi = __builtin_amdgcn_perm(pu[3], pu[2], 0x07060302u);
      s16x4 pb = pack4(lo, hi);   // B-frag: P[key=ct*16+lq*4+j][qrow=lrow]
      union { bf16x8 v8; s16x4 h[2]; } c0, c1;
      c0.v8 = vv[ct*2]; c1.v8 = vv[ct*2+1];
      o[0] = mfma16k(c0.h[0], pb, o[0]);
      o[1] = mfma16k(c0.h[1], pb, o[1]);
      o[2] = mfma16k(c1.h[0], pb, o[2]);
      o[3] = mfma16k(c1.h[1], pb, o[3]);
      dacc = mfma16k(ones, pb, dacc);   // denominator rows
    }
    Kt += 4096; Vp += 4096; ktp += 64;
  }
  size_t rowb = (size_t)(ks*48 + bh) * SEQ + qbase + wave*16 + lrow;
  if (lq == 0) pDen[rowb] = dacc[0];
  #pragma unroll
  for (int nt = 0; nt < 4; nt++){
    float4 ov; ov.x = o[nt][0]; ov.y = o[nt][1]; ov.z = o[nt][2]; ov.w = o[nt][3];
    *(float4*)(pAgg + rowb * 64 + nt*16 + lq*4) = ov;
  }
}

// ---------------- reduce 2 splits + expmap0 + t_new -> bf16 [m][800]
__global__ __launch_bounds__(768) void expmap_pack(const float* __restrict__ pAgg,
    const float* __restrict__ pDen, u16* __restrict__ O){
  __shared__ float th2[NHEADS];
  int m = blockIdx.x, tid = threadIdx.x;
  int h = tid >> 6, lane = tid & 63;
  int b = m >> 10, n = m & 1023, bh = b*NHEADS + h;
  size_t i0 = ((size_t)bh * SEQ + n);
  size_t i1 = ((size_t)(48 + bh) * SEQ + n);
  float d = pDen[i0] + pDen[i1];
  float rden = __builtin_amdgcn_rcpf(d * (1.f + 1e-8f));
  float u = (pAgg[i0*64 + lane] + pAgg[i1*64 + lane]) * rden;
  float n2 = u*u;
  #pragma unroll
  for (int off = 1; off < 64; off <<= 1) n2 += __shfl_xor(n2, off, 64);
  float nn = sqrtf(n2);
  float e = __expf(nn);
  float ch = 0.5f * (e + 1.f/e);
  float sh = 0.5f * (e - 1.f/e);
  float sc = sh / fmaxf(nn, 1e-8f);
  u16* orow = O + (size_t)m * KP1;
  orow[1 + h*64 + lane] = f2bf(u * sc);
  if (lane == 0) th2[h] = ch*ch;
  __syncthreads();
  if (tid == 0){
    float ssum = 0.f;
    #pragma unroll
    for (int i = 0; i < NHEADS; i++) ssum += th2[i];
    orow[0] = f2bf(sqrtf(ssum - 11.f));
  }
  if (tid >= 1 && tid < 32) orow[768 + tid] = 0;
}

// ---------------- sum 4 partials + residual + add_time -> d_out -----
__global__ __launch_bounds__(256) void final_sum(const float* __restrict__ P4,
    const float* __restrict__ out1, float* __restrict__ out){
  __shared__ float red[4];
  int m = blockIdx.x, tid = threadIdx.x;
  float v[3]; float s2 = 0.f;
  #pragma unroll
  for (int j = 0; j < 3; j++){
    int col = tid + j*256;
    float t = out1[(size_t)m*DDIM + col];
    #pragma unroll
    for (int z = 0; z < 4; z++) t += P4[(size_t)z*MROWS*DDIM + (size_t)m*DDIM + col];
    v[j] = t; s2 += t*t;
  }
  s2 = blk_reduce(s2, red, tid);
  float* orow = out + (size_t)m * HID;
  if (tid == 0) orow[0] = sqrtf(1.f + s2);
  #pragma unroll
  for (int j = 0; j < 3; j++) orow[1 + tid + j*256] = v[j];
}

extern "C" void kernel_launch(void* const* d_in, const int* in_sizes, int n_in,
                              void* d_out, int out_size, void* d_ws, size_t ws_size,
                              hipStream_t stream)
{
  (void)in_sizes; (void)n_in; (void)out_size; (void)ws_size;
  const float* x   = (const float*)d_in[0];
  const float* Wq  = (const float*)d_in[1];
  const float* Wk  = (const float*)d_in[2];
  const float* Wv  = (const float*)d_in[3];
  const float* Wo  = (const float*)d_in[4];
  const float* g1p = (const float*)d_in[5];
  const float* b1p = (const float*)d_in[6];
  const float* g2p = (const float*)d_in[7];
  const float* b2p = (const float*)d_in[8];
  const float* Wm1 = (const float*)d_in[9];
  const float* Wm2 = (const float*)d_in[10];
  const float* ar  = (const float*)d_in[11];
  const float* tr  = (const float*)d_in[12];
  const float* lr  = (const float*)d_in[13];

  char* ws = (char*)d_ws;
  // weights [0, 14,598,144)
  u16*   wqb  = (u16*)(ws + 0);          // wk,wv contiguous after (merged B)
  u16*   wob  = (u16*)(ws + 3686400);
  u16*   wm1b = (u16*)(ws + 4915200);
  u16*   wm2b = (u16*)(ws + 9830400);
  u16*   xln  = (u16*)(ws + 14598144);   // 6.55 MB -> 21,151,744
  float* qkv  = (float*)(ws + 21151744); // 37.75 MB -> 58,900,480
  u16*   qp   = (u16*)(ws + 58900480);   // 6.29 MB -> 65,191,936
  u16*   kpk  = (u16*)(ws + 65191936);   // 6.29 MB -> 71,483,392
  u16*   vf   = (u16*)(ws + 71483392);   // 6.29 MB -> 77,774,848
  float* qtb  = (float*)(ws + 77774848); // -> 77,971,456
  float* ktb  = (float*)(ws + 77971456); // -> 78,168,064
  float* pAgg = (float*)(ws + 78168064); // 25.17 MB -> 103,333,888
  float* pDen = (float*)(ws + 103333888);// 393 KB -> 103,727,104
  u16*   woin = (u16*)(ws + 103727104);  // 6.55 MB -> 110,280,704
  float* woP  = (float*)(ws + 21151744); // 50.33 MB, alias qkv..vf (dead) -> 71,483,392
  float* out1 = (float*)(ws + 103727104);// 12.58 MB, alias woin (dead) -> 116,310,016
  u16*   ln2b = (u16*)(ws + 78168064);   // 6.55 MB, alias pAgg (dead)
  u16*   g1b  = (u16*)(ws + 21151744);   // 25.43 MB, alias woP (dead) -> 46,579,712
  float* out2P= (float*)(ws + 46579712); // 50.33 MB -> 96,911,360 (ln2b dead by then)

  conv_all<<<dim3(28512), 256, 0, stream>>>(Wq, Wk, Wv, Wo, Wm1, Wm2, wqb);
  ln_kernel<<<dim3(4096), 256, 0, stream>>>(x, 769, 1, g1p, b1p, xln);
  gemm_split<<<dim3(18, 32, 1), 256, 0, stream>>>(xln, wqb, qkv, 2304, 800);
  pack_qk<<<dim3(1024, 12, 2), 256, 0, stream>>>(qkv, qp, kpk, qtb, ktb);
  pack_v<<<dim3(16, 48), 256, 0, stream>>>(qkv + 1536, vf);
  attn_kernel<<<dim3(16, 48, 2), 256, 0, stream>>>(qp, kpk, vf, qtb, ktb, pAgg, pDen, ar, tr, lr);
  expmap_pack<<<dim3(4096), 768, 0, stream>>>(pAgg, pDen, woin);
  gemm_split<<<dim3(6, 32, 4), 256, 0, stream>>>(woin, wob, woP, 768, 800);
  ln_sum_kernel<<<dim3(4096), 256, 0, stream>>>(woP, x, g2p, b2p, out1, ln2b);
  gemm_gelu<<<dim3(24, 32, 1), 256, 0, stream>>>(ln2b, wm1b, g1b, 3072, 800);
  rowsum<<<dim3(4096), 256, 0, stream>>>(g1b);
  gemm_split<<<dim3(6, 32, 4), 256, 0, stream>>>(g1b, wm2b, out2P, 768, 3104);
  final_sum<<<dim3(4096), 256, 0, stream>>>(out2P, out1, (float*)d_out);
}